// Round 1
// baseline (79.124 us; speedup 1.0000x reference)
//
#include <hip/hip_runtime.h>

#define MARGIN 0.2f
#define BATCH 512
#define FEAT 256

// ---------------------------------------------------------------------------
// Kernel A: pairwise squared distances, 16x16 output tile per 256-thread block.
// pdist[i][j] = sum_f (x_i[f] - x_j[f])^2  (numerically ~= sq_i+sq_j-2*gram)
// LDS rows padded 256->260 floats (1040 B = 16B-aligned row start, and
// (tx*260+f)%32 = (tx*4+f)%32 -> only 2-way bank aliasing, which is free).
// Block (0,0) also zeroes the two global accumulators (d_ws is poisoned 0xAA
// before every timed launch, so this must happen every call; stream ordering
// makes it visible to kernel B).
// ---------------------------------------------------------------------------
__global__ __launch_bounds__(256) void pdist_kernel(const float* __restrict__ X,
                                                    float* __restrict__ pdist,
                                                    float* __restrict__ acc) {
    __shared__ float Xi[16][260];
    __shared__ float Xj[16][260];
    const int tx = threadIdx.x, ty = threadIdx.y;
    const int tid = ty * 16 + tx;
    const int i0 = blockIdx.y * 16, j0 = blockIdx.x * 16;

    // Load 16 rows x 256 floats for each tile = 1024 float4 per tile.
    const float4* X4 = (const float4*)X;  // 64 float4 per row
#pragma unroll
    for (int c = 0; c < 4; ++c) {
        int idx = tid + c * 256;      // 0..1023
        int row = idx >> 6;
        int col = idx & 63;
        float4 vi = X4[(i0 + row) * 64 + col];
        float4 vj = X4[(j0 + row) * 64 + col];
        *(float4*)&Xi[row][col * 4] = vi;
        *(float4*)&Xj[row][col * 4] = vj;
    }
    __syncthreads();

    float s = 0.f;
#pragma unroll 8
    for (int f = 0; f < FEAT; ++f) {
        float d = Xi[ty][f] - Xj[tx][f];
        s = fmaf(d, d, s);
    }
    pdist[(i0 + ty) * BATCH + (j0 + tx)] = s;

    if (tid == 0 && blockIdx.x == 0 && blockIdx.y == 0) {
        acc[0] = 0.f;   // hinge sum
        acc[1] = 0.f;   // valid-triplet count
    }
}

// ---------------------------------------------------------------------------
// Kernel B: one block per anchor i. Compact positives/negatives of row i into
// LDS lists (order irrelevant for a sum), then dense cp*cn hinge reduction.
// mask(i,j,k) = [y_j==y_i && j!=i] * [y_k!=y_i]  (j!=k, i!=k implied).
// ---------------------------------------------------------------------------
__global__ __launch_bounds__(256) void triplet_kernel(const float* __restrict__ pdist,
                                                      const int* __restrict__ y,
                                                      float* __restrict__ acc) {
    __shared__ float pos_s[BATCH];   // d(i,j)+margin for valid j
    __shared__ float neg_s[BATCH];   // d(i,k) for valid k
    __shared__ int   cnt_s[2];
    __shared__ float wsum[4];

    const int i = blockIdx.x;
    const int tid = threadIdx.x;
    if (tid < 2) cnt_s[tid] = 0;
    __syncthreads();

    const int yi = y[i];
    const float* drow = pdist + (size_t)i * BATCH;
    for (int j = tid; j < BATCH; j += 256) {
        int yj = y[j];
        float dj = drow[j];
        if (yj != yi) {
            int n = atomicAdd(&cnt_s[1], 1);
            neg_s[n] = dj;
        } else if (j != i) {
            int p = atomicAdd(&cnt_s[0], 1);
            pos_s[p] = dj + MARGIN;
        }
    }
    __syncthreads();

    const int cp = cnt_s[0], cn = cnt_s[1];
    float s = 0.f;
    for (int jj = 0; jj < cp; ++jj) {          // ~8 iterations, uniform
        float dp = pos_s[jj];                  // LDS broadcast
        for (int k = tid; k < cn; k += 256) {  // consecutive -> conflict-free
            s += fmaxf(dp - neg_s[k], 0.f);
        }
    }

    // wave(64) shuffle reduce, then 4 waves via LDS
#pragma unroll
    for (int off = 32; off > 0; off >>= 1) s += __shfl_down(s, off);
    if ((tid & 63) == 0) wsum[tid >> 6] = s;
    __syncthreads();
    if (tid == 0) {
        float bs = wsum[0] + wsum[1] + wsum[2] + wsum[3];
        atomicAdd(&acc[0], bs);
        atomicAdd(&acc[1], (float)(cp * cn));  // exact: < 2^24
    }
}

// ---------------------------------------------------------------------------
// Kernel C: final divide.
// ---------------------------------------------------------------------------
__global__ void finalize_kernel(const float* __restrict__ acc, float* __restrict__ out) {
    out[0] = acc[0] / acc[1];
}

extern "C" void kernel_launch(void* const* d_in, const int* in_sizes, int n_in,
                              void* d_out, int out_size, void* d_ws, size_t ws_size,
                              hipStream_t stream) {
    const float* X = (const float*)d_in[0];   // [512, 256] fp32
    const int*   y = (const int*)d_in[1];     // [512] int
    float* out = (float*)d_out;               // scalar fp32

    float* pdist = (float*)d_ws;                      // 512*512 floats = 1 MB
    float* acc   = pdist + (size_t)BATCH * BATCH;     // 2 floats

    dim3 gA(BATCH / 16, BATCH / 16), bA(16, 16);
    pdist_kernel<<<gA, bA, 0, stream>>>(X, pdist, acc);

    triplet_kernel<<<BATCH, 256, 0, stream>>>(pdist, y, acc);

    finalize_kernel<<<1, 1, 0, stream>>>(acc, out);
}